// Round 3
// baseline (352.020 us; speedup 1.0000x reference)
//
#include <hip/hip_runtime.h>

// Unfold: x[B=32, C=64, H=64, W=64] fp32, KH=KW=3, stride=1
// out[b][c*9 + i*3 + j][ho*62 + wo] = x[b][c][ho+i][wo+j]; out [32, 576, 3844].
//
// Row-wave design: one block per (b,c); each wave owns output row ho
// (ho += 4 across the 4 waves). With wo = lane, the source column is
// lane + j <= 63, so there is NO row wrap, NO division, NO LDS, NO
// __syncthreads, NO swizzle. Per (k, ho): one coalesced 248 B load
// (L1-hot: each wave's working set is 3 rows = 768 B) and one coalesced
// 248 B store. Lanes 62-63 are exec-masked off (3% waste).
//
// Issue model: 18 VMEM instr / row-wave; 9216 VMEM instr per CU ~ 15 us.
// => kernel should be HBM-write-bound (~283 MB / 6.3 TB/s ~ 45-55 us).
// Plain (cached) stores: 248 B chunks leave partial 64 B edge lines that
// L2 merges across adjacent waves; nontemporal would force partial-line
// HBM writes (DRAM read-modify-write), so nt is deliberately NOT used.

#define B 32
#define C 64
#define H 64
#define W 64
#define HO 62
#define WO 62
#define L (HO * WO)   // 3844
#define KK 9          // KH*KW

__global__ __launch_bounds__(256) void unfold_kernel(
    const float* __restrict__ x, float* __restrict__ out) {
    const int c    = blockIdx.x;        // 0..63
    const int b    = blockIdx.y;        // 0..31
    const int tid  = threadIdx.x;       // 0..255
    const int wid  = tid >> 6;          // wave id 0..3
    const int lane = tid & 63;          // 0..63

    const float* __restrict__ xr = x + (((size_t)(b * C + c)) << 12);
    float* __restrict__ o = out + (size_t)(b * C + c) * KK * L;

    if (lane < WO) {                    // lanes 62,63 idle (exec mask)
        for (int ho = wid; ho < HO; ho += 4) {
            const float* __restrict__ row0 = xr + ho * W + lane;
            float* __restrict__ orow = o + ho * WO + lane;
#pragma unroll
            for (int i = 0; i < 3; ++i) {
                const float* __restrict__ ri = row0 + i * W;
#pragma unroll
                for (int j = 0; j < 3; ++j) {
                    // load: x[ho+i][lane+j], coalesced 248 B, L1-hot
                    // store: out plane (i*3+j), row ho, coalesced 248 B
                    orow[(i * 3 + j) * L] = ri[j];
                }
            }
        }
    }
}

extern "C" void kernel_launch(void* const* d_in, const int* in_sizes, int n_in,
                              void* d_out, int out_size, void* d_ws, size_t ws_size,
                              hipStream_t stream) {
    const float* x = (const float*)d_in[0];
    float* out = (float*)d_out;

    dim3 block(256, 1, 1);
    dim3 grid(C, B, 1);  // one block per (b,c) channel: 2048 blocks
    unfold_kernel<<<grid, block, 0, stream>>>(x, out);
}

// Round 4
// 314.003 us; speedup vs baseline: 1.1211x; 1.1211x over previous
//
#include <hip/hip_runtime.h>

// Unfold: x[B=32, C=64, H=64, W=64] fp32, KH=KW=3, stride=1
// out[b][c*9 + i*3 + j][ho*62 + wo] = x[b][c][ho+i][wo+j]; out [32, 576, 3844].
//
// One block per (b,c) channel. Stage the 16 KB channel in LDS (read from
// HBM exactly once), then write the 9 output planes k-OUTER: each plane is
// a single contiguous ~15.4 KB dwordx4 stream per block (proven best store
// order; nt-stores and scalar stores both measured slower). LDS uses a
// +1-pad-per-32-floats swizzle (idx -> idx + (idx>>5)): stride-4-float
// access = free 2-way pattern, SQ_LDS_BANK_CONFLICT measured 0.
//
// New vs round-0: the ho/wo decode (magic-div + row-wrap chain) is hoisted
// out of the k-loop — computed ONCE per thread into A[4][4] registers
// (4 positions x 4 unswizzled addresses, statically indexed after unroll),
// reused by all 9 planes with a compile-time +base and re-swizzle. Cuts
// emit VALU ~3x while keeping round-0's exact memory pattern.

#define B 32
#define C 64
#define H 64
#define W 64
#define HO 62
#define WO 62
#define L (HO * WO)   // 3844
#define L4 (L / 4)    // 961
#define KK 9          // KH*KW

typedef float f32x4 __attribute__((ext_vector_type(4)));

__device__ __forceinline__ int sw(int p) { return p + (p >> 5); }

__global__ __launch_bounds__(256) void unfold_kernel(
    const float* __restrict__ x, float* __restrict__ out) {
    __shared__ float tile[H * W + (H * W) / 32];  // 4096 + 128 floats = 16.9 KB

    const int c   = blockIdx.x;   // 0..63
    const int b   = blockIdx.y;   // 0..31
    const int tid = threadIdx.x;  // 0..255

    // ---- Stage channel (b,c): 4096 floats = 1024 float4, coalesced. ----
    const f32x4* __restrict__ src =
        (const f32x4*)(x + (((size_t)(b * C + c)) << 12));
#pragma unroll
    for (int r = 0; r < 4; ++r) {
        const int p4 = tid + r * 256;  // 0..1023
        f32x4 v = src[p4];
        const int p = p4 * 4;
        tile[sw(p)]     = v.x;   // stride-4 writes: conflict-free under swizzle
        tile[sw(p + 1)] = v.y;
        tile[sw(p + 2)] = v.z;
        tile[sw(p + 3)] = v.w;
    }

    // ---- Decode positions once (independent of k): 4 per thread. ----
    int A[4][4];                       // unswizzled input addrs, static-indexed
#pragma unroll
    for (int r = 0; r < 4; ++r) {
        const int t = tid + r * 256;   // float4 index within a k-plane
        if (t < L4) {                  // r<3 always true; r==3: tid<193
            const int l0 = t * 4;
            int ho = l0 / WO;          // magic-mul division (once per position)
            int wo = l0 - ho * WO;
            int a  = ho * W + wo;
            A[r][0] = a; ++a; ++wo; if (wo == WO) { wo = 0; a += (W - WO); }
            A[r][1] = a; ++a; ++wo; if (wo == WO) { wo = 0; a += (W - WO); }
            A[r][2] = a; ++a; ++wo; if (wo == WO) { wo = 0; a += (W - WO); }
            A[r][3] = a;
        }
    }
    __syncthreads();

    // ---- Emit: k-outer (one contiguous plane stream at a time). ----
    f32x4* __restrict__ dst =
        (f32x4*)out + (size_t)(b * C + c) * KK * L4;

#pragma unroll
    for (int k = 0; k < KK; ++k) {
        const int i    = k / 3;          // constants after unroll
        const int j    = k - i * 3;
        const int base = i * W + j;      // 0,1,2,64,65,66,128,129,130
#pragma unroll
        for (int r = 0; r < 4; ++r) {
            const int t = tid + r * 256;
            if (t < L4) {
                f32x4 v;
                v.x = tile[sw(A[r][0] + base)];
                v.y = tile[sw(A[r][1] + base)];
                v.z = tile[sw(A[r][2] + base)];
                v.w = tile[sw(A[r][3] + base)];
                dst[k * L4 + t] = v;     // coalesced, cached dwordx4 stream
            }
        }
    }
}

extern "C" void kernel_launch(void* const* d_in, const int* in_sizes, int n_in,
                              void* d_out, int out_size, void* d_ws, size_t ws_size,
                              hipStream_t stream) {
    const float* x = (const float*)d_in[0];
    float* out = (float*)d_out;

    dim3 block(256, 1, 1);
    dim3 grid(C, B, 1);  // one block per (b,c) channel: 2048 blocks
    unfold_kernel<<<grid, block, 0, stream>>>(x, out);
}